// Round 5
// baseline (302.914 us; speedup 1.0000x reference)
//
#include <hip/hip_runtime.h>
#include <math.h>

// EngineOrderFFT via batched Bluestein, fully LDS-resident per row.
// |X| = |conv[:, :K]|. M=16384 as 128x128 four-step inside ONE workgroup.
// R4: pair-interleaved halves (ILP across the two 64-FFT groups), LDS twiddle
// tables + cmul chains replacing sincos, chirp-build recurrence, zero-half
// trim, 256 blocks x 2 rows with Bhat/table reuse.

static constexpr int Bn = 64;
static constexpr int Nn = 8192;
static constexpr int Mm = 16384;

#define PI_F 3.14159265358979323846f
#define TWO_PI_F 6.28318530717958647692f
#define R2_F 0.70710678118654752f

__device__ __forceinline__ int compute_n(float rpm) {
    // ref: pad = floor((40*60/rpm - 1)*8192) in f32; n = 8192 + pad
    return 8192 + (int)floorf((2400.0f / rpm - 1.0f) * 8192.0f);
}
__device__ __forceinline__ float2 cmul(float2 a, float2 b) {
    return make_float2(a.x*b.x - a.y*b.y, a.x*b.y + a.y*b.x);
}
__device__ __forceinline__ float2 cadd(float2 a, float2 b){ return make_float2(a.x+b.x, a.y+b.y); }
__device__ __forceinline__ float2 csub(float2 a, float2 b){ return make_float2(a.x-b.x, a.y-b.y); }
__device__ __forceinline__ float2 shflx1(float2 v) {
    return make_float2(__shfl_xor(v.x, 1, 64), __shfl_xor(v.y, 1, 64));
}

#define BF(lo,hi,tw) { float2 _d = csub(lo,hi); lo = cadd(lo,hi); hi = cmul(_d, tw); }
#define BT(lo,hi,tw) { float2 _b = cmul(hi,tw); hi = csub(lo,_b); lo = cadd(lo,_b); }
#define SELC(r,c0,s0,c1,s1) ((r) ? make_float2(c1,s1) : make_float2(c0,s0))

// element (r,c) of the 128x128 tile; XOR swizzle keeps all access patterns
// (rows, cols, bitrev-pos rows/cols, linear) at the wave64-b64 floor.
__device__ __forceinline__ int bigidx(int r, int c) {
    int sw = ((r & 15) ^ ((r >> 4) << 1) ^ ((c >> 4) << 1)) & 15;
    return (r << 7) + (c ^ sw);
}

struct ColAddr { int c; };   // sub-FFT along rows (fixed column)
struct RowAddr { int r; };   // sub-FFT along cols (fixed row)
__device__ __forceinline__ int addr_of(ColAddr a, int u) { return bigidx(u, a.c); }
__device__ __forceinline__ int addr_of(RowAddr a, int u) { return bigidx(a.r, u); }

// W_M^{-m} from 2-level tables (Whi[m]=exp(-i*pi*m/64), Wlo[m]=exp(-i*pi*m/8192))
__device__ __forceinline__ float2 wtab(const float2* Whi, const float2* Wlo, int m) {
    return cmul(Whi[m >> 7], Wlo[m & 127]);
}

// ================= single-call cores (used by bhat builder only) =============
template<class AD>
__device__ __forceinline__ void dif128(float2 v[8], float2* L, AD ad, int p) {
    float sn, cs;
    __sincosf(PI_F * (float)p * (1.0f/64.0f), &sn, &cs);
    float2 w1 = make_float2(cs, -sn);
    float2 w2 = cmul(w1, w1);
    float2 w4 = cmul(w2, w2);
    BF(v[0],v[4], w1);
    BF(v[1],v[5], cmul(w1, make_float2(R2_F,-R2_F)));
    BF(v[2],v[6], make_float2(w1.y, -w1.x));
    BF(v[3],v[7], cmul(w1, make_float2(-R2_F,-R2_F)));
    float2 w2i = make_float2(w2.y, -w2.x);
    BF(v[0],v[2], w2);  BF(v[1],v[3], w2i);
    BF(v[4],v[6], w2);  BF(v[5],v[7], w2i);
    BF(v[0],v[1], w4);  BF(v[2],v[3], w4);
    BF(v[4],v[5], w4);  BF(v[6],v[7], w4);
    #pragma unroll
    for (int q = 0; q < 8; ++q) L[addr_of(ad, p + 16*q)] = v[q];
    int bb = p >> 1, r = p & 1;
    #pragma unroll
    for (int s = 0; s < 8; ++s) v[s] = L[addr_of(ad, 16*bb + r + 2*s)];
    BF(v[0],v[4], SELC(r, 1.f,0.f,                    0.92387953f,-0.38268343f));
    BF(v[1],v[5], SELC(r, 0.70710678f,-0.70710678f,   0.38268343f,-0.92387953f));
    BF(v[2],v[6], SELC(r, 0.f,-1.f,                  -0.38268343f,-0.92387953f));
    BF(v[3],v[7], SELC(r, -0.70710678f,-0.70710678f, -0.92387953f,-0.38268343f));
    BF(v[0],v[2], SELC(r, 1.f,0.f,  0.70710678f,-0.70710678f));
    BF(v[1],v[3], SELC(r, 0.f,-1.f, -0.70710678f,-0.70710678f));
    BF(v[4],v[6], SELC(r, 1.f,0.f,  0.70710678f,-0.70710678f));
    BF(v[5],v[7], SELC(r, 0.f,-1.f, -0.70710678f,-0.70710678f));
    #pragma unroll
    for (int s = 0; s < 8; s += 2) {
        float2 d = csub(v[s], v[s+1]);
        v[s] = cadd(v[s], v[s+1]);
        v[s+1] = r ? make_float2(d.y, -d.x) : d;
    }
    #pragma unroll
    for (int s = 0; s < 8; ++s) {
        float2 o = shflx1(v[s]);
        v[s] = r ? csub(o, v[s]) : cadd(v[s], o);
    }
}

// ================= paired cores (main kernel) =============
// HZ: inputs v[h][4..7] are implicit zeros (not loaded).
template<bool HZ, class AD>
__device__ __forceinline__ void dif128p(float2 v[2][8], float2* L, AD ad0, AD ad1,
                                        int p, const float2* sWhi) {
    float2 w1 = sWhi[p];                        // exp(-i*pi*p/64)
    float2 w2 = cmul(w1, w1);
    float2 w4 = cmul(w2, w2);
    float2 w1b = cmul(w1, make_float2(R2_F,-R2_F));
    float2 w1c = make_float2(w1.y, -w1.x);
    float2 w1d = cmul(w1, make_float2(-R2_F,-R2_F));
    float2 w2i = make_float2(w2.y, -w2.x);
    #pragma unroll
    for (int h = 0; h < 2; ++h) {
        if (HZ) {
            v[h][4] = cmul(v[h][0], w1);
            v[h][5] = cmul(v[h][1], w1b);
            v[h][6] = cmul(v[h][2], w1c);
            v[h][7] = cmul(v[h][3], w1d);
        } else {
            BF(v[h][0],v[h][4], w1);
            BF(v[h][1],v[h][5], w1b);
            BF(v[h][2],v[h][6], w1c);
            BF(v[h][3],v[h][7], w1d);
        }
        BF(v[h][0],v[h][2], w2);  BF(v[h][1],v[h][3], w2i);
        BF(v[h][4],v[h][6], w2);  BF(v[h][5],v[h][7], w2i);
        BF(v[h][0],v[h][1], w4);  BF(v[h][2],v[h][3], w4);
        BF(v[h][4],v[h][5], w4);  BF(v[h][6],v[h][7], w4);
    }
    #pragma unroll
    for (int q = 0; q < 8; ++q) L[addr_of(ad0, p + 16*q)] = v[0][q];
    #pragma unroll
    for (int q = 0; q < 8; ++q) L[addr_of(ad1, p + 16*q)] = v[1][q];
    int bb = p >> 1, r = p & 1;
    #pragma unroll
    for (int s = 0; s < 8; ++s) v[0][s] = L[addr_of(ad0, 16*bb + r + 2*s)];
    #pragma unroll
    for (int s = 0; s < 8; ++s) v[1][s] = L[addr_of(ad1, 16*bb + r + 2*s)];
    #pragma unroll
    for (int h = 0; h < 2; ++h) {
        BF(v[h][0],v[h][4], SELC(r, 1.f,0.f,                    0.92387953f,-0.38268343f));
        BF(v[h][1],v[h][5], SELC(r, 0.70710678f,-0.70710678f,   0.38268343f,-0.92387953f));
        BF(v[h][2],v[h][6], SELC(r, 0.f,-1.f,                  -0.38268343f,-0.92387953f));
        BF(v[h][3],v[h][7], SELC(r, -0.70710678f,-0.70710678f, -0.92387953f,-0.38268343f));
        BF(v[h][0],v[h][2], SELC(r, 1.f,0.f,  0.70710678f,-0.70710678f));
        BF(v[h][1],v[h][3], SELC(r, 0.f,-1.f, -0.70710678f,-0.70710678f));
        BF(v[h][4],v[h][6], SELC(r, 1.f,0.f,  0.70710678f,-0.70710678f));
        BF(v[h][5],v[h][7], SELC(r, 0.f,-1.f, -0.70710678f,-0.70710678f));
        #pragma unroll
        for (int s = 0; s < 8; s += 2) {
            float2 d = csub(v[h][s], v[h][s+1]);
            v[h][s] = cadd(v[h][s], v[h][s+1]);
            v[h][s+1] = r ? make_float2(d.y, -d.x) : d;
        }
        #pragma unroll
        for (int s = 0; s < 8; ++s) {
            float2 o = shflx1(v[h][s]);
            v[h][s] = r ? csub(o, v[h][s]) : cadd(v[h][s], o);
        }
    }
}

// HOUT: only lo outputs v[h][0..3] of the final stage are produced.
template<bool HOUT, class AD>
__device__ __forceinline__ void dit128p(float2 v[2][8], float2* L, AD ad0, AD ad1,
                                        int p, const float2* sWhi) {
    int bb = p >> 1, r = p & 1;
    #pragma unroll
    for (int h = 0; h < 2; ++h) {
        #pragma unroll
        for (int s = 0; s < 8; ++s) {
            float2 o = shflx1(v[h][s]);
            v[h][s] = r ? csub(o, v[h][s]) : cadd(v[h][s], o);
        }
        #pragma unroll
        for (int s = 0; s < 8; s += 2) {
            float2 bq = v[h][s+1];
            if (r) bq = make_float2(-bq.y, bq.x);
            v[h][s+1] = csub(v[h][s], bq);
            v[h][s] = cadd(v[h][s], bq);
        }
        BT(v[h][0],v[h][2], SELC(r, 1.f,0.f,  0.70710678f,0.70710678f));
        BT(v[h][1],v[h][3], SELC(r, 0.f,1.f, -0.70710678f,0.70710678f));
        BT(v[h][4],v[h][6], SELC(r, 1.f,0.f,  0.70710678f,0.70710678f));
        BT(v[h][5],v[h][7], SELC(r, 0.f,1.f, -0.70710678f,0.70710678f));
        BT(v[h][0],v[h][4], SELC(r, 1.f,0.f,                   0.92387953f,0.38268343f));
        BT(v[h][1],v[h][5], SELC(r, 0.70710678f,0.70710678f,   0.38268343f,0.92387953f));
        BT(v[h][2],v[h][6], SELC(r, 0.f,1.f,                  -0.38268343f,0.92387953f));
        BT(v[h][3],v[h][7], SELC(r, -0.70710678f,0.70710678f, -0.92387953f,0.38268343f));
    }
    #pragma unroll
    for (int s = 0; s < 8; ++s) L[addr_of(ad0, 16*bb + r + 2*s)] = v[0][s];
    #pragma unroll
    for (int s = 0; s < 8; ++s) L[addr_of(ad1, 16*bb + r + 2*s)] = v[1][s];
    #pragma unroll
    for (int q = 0; q < 8; ++q) v[0][q] = L[addr_of(ad0, p + 16*q)];
    #pragma unroll
    for (int q = 0; q < 8; ++q) v[1][q] = L[addr_of(ad1, p + 16*q)];
    float2 w1 = make_float2(sWhi[p].x, -sWhi[p].y);   // exp(+i*pi*p/64)
    float2 w2 = cmul(w1, w1);
    float2 w4 = cmul(w2, w2);
    float2 w2j = make_float2(-w2.y, w2.x);
    float2 w1b = cmul(w1, make_float2(R2_F, R2_F));
    float2 w1c = make_float2(-w1.y, w1.x);
    float2 w1d = cmul(w1, make_float2(-R2_F, R2_F));
    #pragma unroll
    for (int h = 0; h < 2; ++h) {
        BT(v[h][0],v[h][1], w4); BT(v[h][2],v[h][3], w4);
        BT(v[h][4],v[h][5], w4); BT(v[h][6],v[h][7], w4);
        BT(v[h][0],v[h][2], w2);  BT(v[h][1],v[h][3], w2j);
        BT(v[h][4],v[h][6], w2);  BT(v[h][5],v[h][7], w2j);
        if (HOUT) {
            v[h][0] = cadd(v[h][0], cmul(v[h][4], w1));
            v[h][1] = cadd(v[h][1], cmul(v[h][5], w1b));
            v[h][2] = cadd(v[h][2], cmul(v[h][6], w1c));
            v[h][3] = cadd(v[h][3], cmul(v[h][7], w1d));
        } else {
            BT(v[h][0],v[h][4], w1);
            BT(v[h][1],v[h][5], w1b);
            BT(v[h][2],v[h][6], w1c);
            BT(v[h][3],v[h][7], w1d);
        }
    }
}

// ---------------- Bhat builder: one block per b (as R3, known correct) ------
__global__ __launch_bounds__(1024) void eofft_bhat(const float* __restrict__ rpm,
                                                   float2* __restrict__ bhat) {
    extern __shared__ float2 L[];
    int tid = threadIdx.x;
    int f = tid >> 4, p = tid & 15;
    int b = blockIdx.x;
    int n = compute_n(rpm[b]);
    int two_n = 2 * n;
    float inv_n = 1.0f / (float)n;

    #pragma unroll
    for (int i = 0; i < 16; ++i) {
        int t = i * 1024 + tid;
        int mm = min(t, Mm - t);
        int ph = (mm * mm) % two_n;
        float sn, cs; __sincosf(PI_F * (float)ph * inv_n, &sn, &cs);
        L[bigidx(t >> 7, t & 127)] = make_float2(cs, sn);   // exp(+i b_phase)
    }
    __syncthreads();
    #pragma unroll
    for (int c0 = 0; c0 < 128; c0 += 64) {
        int t1 = c0 + f;
        float2 v[8];
        #pragma unroll
        for (int q = 0; q < 8; ++q) v[q] = L[bigidx(p + 16*q, t1)];
        dif128(v, L, ColAddr{t1}, p);
        int bb = p >> 1, r = p & 1;
        #pragma unroll
        for (int s = 0; s < 8; ++s) {
            int j = 16*bb + r + 2*s;
            int k2 = __brev((unsigned)j) >> 25;
            float sn, cs;
            __sincosf(-TWO_PI_F * (float)(t1 * k2) * (1.0f/16384.0f), &sn, &cs);
            L[bigidx(j, t1)] = cmul(v[s], make_float2(cs, sn));
        }
    }
    __syncthreads();
    #pragma unroll
    for (int r0 = 0; r0 < 128; r0 += 64) {
        int j = r0 + f;
        float2 v[8];
        #pragma unroll
        for (int q = 0; q < 8; ++q) v[q] = L[bigidx(j, p + 16*q)];
        dif128(v, L, RowAddr{j}, p);
        float2* bo = bhat + ((size_t)b << 14) + (j << 7) + (p << 3);
        #pragma unroll
        for (int s = 0; s < 8; ++s) bo[s] = v[s];
    }
}

// ---------------- main: one block per (b, ch-pair), 2 rows per block --------
__global__ __launch_bounds__(1024, 4) void eofft_main(const float* __restrict__ x,
                                                      const float* __restrict__ rpm,
                                                      const float2* __restrict__ bhat,
                                                      float* __restrict__ out) {
    extern __shared__ float2 L[];
    __shared__ float2 sWhi[128];
    __shared__ float2 sWlo[128];
    int tid = threadIdx.x;
    int f = tid >> 4, p = tid & 15;
    int bb = p >> 1, r = p & 1;
    int b = blockIdx.x & 63;
    int cpair = blockIdx.x >> 6;

    if (tid < 128) {
        float sn, cs; __sincosf(PI_F * (float)tid * (1.0f/64.0f), &sn, &cs);
        sWhi[tid] = make_float2(cs, -sn);
    } else if (tid < 256) {
        int m = tid - 128;
        float sn, cs; __sincosf(PI_F * (float)m * (1.0f/8192.0f), &sn, &cs);
        sWlo[m] = make_float2(cs, -sn);
    }
    int n = compute_n(rpm[b]);
    int two_n = 2 * n;
    float inv_n = 1.0f / (float)n;
    // chirp quadratic-phase recurrence constants (t steps by 1024)
    float sn, cs;
    __sincosf(PI_F * (float)((tid * tid) % two_n) * inv_n, &sn, &cs);
    float2 u_init = make_float2(cs, -sn);
    __sincosf(PI_F * (float)((2048 * tid + 1048576) % two_n) * inv_n, &sn, &cs);
    float2 d_init = make_float2(cs, -sn);
    __sincosf(PI_F * (float)(2097152 % two_n) * inv_n, &sn, &cs);
    float2 Cst = make_float2(cs, -sn);

    for (int rr = 0; rr < 2; ++rr) {
        int ch = cpair * 2 + rr;
        __syncthreads();   // L free of previous row's readers (also orders tables)
        // ---- build a = x * exp(-i a_phase); rows t2>=64 stay untouched (HZ)
        {
            const float* xb = x + ((size_t)b << 16) + ch;
            float2 u = u_init, dd = d_init;
            #pragma unroll
            for (int i = 0; i < 8; ++i) {
                int t = i * 1024 + tid;              // t = t1 + 128*t2 < 8192
                float xv = xb[(size_t)t << 3];
                L[bigidx(t >> 7, t & 127)] = make_float2(xv * u.x, xv * u.y);
                u = cmul(u, dd); dd = cmul(dd, Cst);
            }
        }
        __syncthreads();
        float2 v[2][8];
        // ---- phase A: fwd FFT over t2, cols f and f+64 paired; twiddle chain
        #pragma unroll
        for (int q = 0; q < 4; ++q) {
            v[0][q] = L[bigidx(p + 16*q, f)];
            v[1][q] = L[bigidx(p + 16*q, f + 64)];
        }
        dif128p<true>(v, L, ColAddr{f}, ColAddr{f + 64}, p, sWhi);
        {
            int k2base = __brev((unsigned)(16*bb + r)) >> 25;
            #pragma unroll
            for (int h = 0; h < 2; ++h) {
                int t1 = f + 64*h;
                float2 cur = wtab(sWhi, sWlo, t1 * k2base);
                float2 w8  = wtab(sWhi, sWlo, 8 * t1);
                #pragma unroll
                for (int e = 0; e < 8; ++e) {
                    const int s = ((e & 1) << 2) | (e & 2) | ((e & 4) >> 2); // brev3(e)
                    L[bigidx(16*bb + r + 2*s, t1)] = cmul(v[h][s], cur);
                    cur = cmul(cur, w8);
                }
            }
        }
        __syncthreads();
        // ---- phase B: rows f and f+64: fwd over t1, *Bhat, inv over k1, twiddle
        {
            const float2* bhp = bhat + ((size_t)b << 14) + (p << 3);
            float2 bh[2][8];
            #pragma unroll
            for (int s = 0; s < 8; ++s) bh[0][s] = bhp[((size_t)f << 7) + s];
            #pragma unroll
            for (int s = 0; s < 8; ++s) bh[1][s] = bhp[((size_t)(f + 64) << 7) + s];
            #pragma unroll
            for (int q = 0; q < 8; ++q) {
                v[0][q] = L[bigidx(f, p + 16*q)];
                v[1][q] = L[bigidx(f + 64, p + 16*q)];
            }
            dif128p<false>(v, L, RowAddr{f}, RowAddr{f + 64}, p, sWhi);
            #pragma unroll
            for (int h = 0; h < 2; ++h)
                #pragma unroll
                for (int s = 0; s < 8; ++s) v[h][s] = cmul(v[h][s], bh[h][s]);
            dit128p<false>(v, L, RowAddr{f}, RowAddr{f + 64}, p, sWhi);
            #pragma unroll
            for (int h = 0; h < 2; ++h) {
                int j = f + 64*h;
                int k2v = __brev((unsigned)j) >> 25;
                float2 cur = wtab(sWhi, sWlo, k2v * p);
                float2 w16 = wtab(sWhi, sWlo, 16 * k2v);
                #pragma unroll
                for (int q = 0; q < 8; ++q) {
                    // * exp(+2pi i k2 t1/M) = conj(cur)
                    L[bigidx(j, p + 16*q)] = cmul(v[h][q], make_float2(cur.x, -cur.y));
                    cur = cmul(cur, w16);
                }
            }
        }
        __syncthreads();
        // ---- phase C: inverse FFT over k2 per column; keep t2 < 64; |.|/M
        #pragma unroll
        for (int s = 0; s < 8; ++s) {
            v[0][s] = L[bigidx(16*bb + r + 2*s, f)];
            v[1][s] = L[bigidx(16*bb + r + 2*s, f + 64)];
        }
        dit128p<true>(v, L, ColAddr{f}, ColAddr{f + 64}, p, sWhi);
        #pragma unroll
        for (int h = 0; h < 2; ++h) {
            int t1 = f + 64*h;
            float* ob = out + (((size_t)(b << 13) + t1) << 3) + ch;
            #pragma unroll
            for (int q = 0; q < 4; ++q) {
                int t2 = p + 16*q;
                float2 z = v[h][q];
                ob[(size_t)t2 << 10] = sqrtf(z.x*z.x + z.y*z.y) * (1.0f/16384.0f);
            }
        }
    }
}

// ---------------- launch ----------------
extern "C" void kernel_launch(void* const* d_in, const int* in_sizes, int n_in,
                              void* d_out, int out_size, void* d_ws, size_t ws_size,
                              hipStream_t stream) {
    const float* x   = (const float*)d_in[0];
    const float* rpm = (const float*)d_in[1];
    float* outF = (float*)d_out;
    float2* bhat = (float2*)d_ws;                    // 64*16384 float2 = 8 MiB

    eofft_bhat<<<Bn, 1024, 131072, stream>>>(rpm, bhat);
    eofft_main<<<Bn * 4, 1024, 131072, stream>>>(x, rpm, bhat, outF);
}

// Round 6
// 130.430 us; speedup vs baseline: 2.3224x; 2.3224x over previous
//
#include <hip/hip_runtime.h>
#include <math.h>

// EngineOrderFFT via batched Bluestein, fully LDS-resident per row.
// |X| = |conv[:, :K]|. M=16384 as 128x128 four-step inside ONE workgroup.
// R5: 512-thread blocks, each thread owns 4 sub-FFT halves (v[4][8]) =>
// 4-way ILP across the LDS mid-transpose drains, with __launch_bounds__(512,2)
// giving a 256-VGPR budget (R4's 2-way pairing at 1024 threads spilled).
// Keeps R4's verified math: LDS twiddle tables + cmul chains (no sincos in
// hot path), chirp-build quadratic recurrence, zero-half input trim (HZ),
// discarded-half output trim (HOUT).

static constexpr int Bn = 64;
static constexpr int Nn = 8192;
static constexpr int Mm = 16384;

#define PI_F 3.14159265358979323846f
#define TWO_PI_F 6.28318530717958647692f
#define R2_F 0.70710678118654752f

__device__ __forceinline__ int compute_n(float rpm) {
    // ref: pad = floor((40*60/rpm - 1)*8192) in f32; n = 8192 + pad
    return 8192 + (int)floorf((2400.0f / rpm - 1.0f) * 8192.0f);
}
__device__ __forceinline__ float2 cmul(float2 a, float2 b) {
    return make_float2(a.x*b.x - a.y*b.y, a.x*b.y + a.y*b.x);
}
__device__ __forceinline__ float2 cadd(float2 a, float2 b){ return make_float2(a.x+b.x, a.y+b.y); }
__device__ __forceinline__ float2 csub(float2 a, float2 b){ return make_float2(a.x-b.x, a.y-b.y); }
__device__ __forceinline__ float2 shflx1(float2 v) {
    return make_float2(__shfl_xor(v.x, 1, 64), __shfl_xor(v.y, 1, 64));
}

#define BF(lo,hi,tw) { float2 _d = csub(lo,hi); lo = cadd(lo,hi); hi = cmul(_d, tw); }
#define BT(lo,hi,tw) { float2 _b = cmul(hi,tw); hi = csub(lo,_b); lo = cadd(lo,_b); }
#define SELC(r,c0,s0,c1,s1) ((r) ? make_float2(c1,s1) : make_float2(c0,s0))

// element (r,c) of the 128x128 tile; XOR swizzle keeps all access patterns
// (rows, cols, bitrev-pos rows/cols, linear) at the wave64-b64 floor.
__device__ __forceinline__ int bigidx(int r, int c) {
    int sw = ((r & 15) ^ ((r >> 4) << 1) ^ ((c >> 4) << 1)) & 15;
    return (r << 7) + (c ^ sw);
}

struct ColAddr { int c; };   // sub-FFT along rows (fixed column)
struct RowAddr { int r; };   // sub-FFT along cols (fixed row)
__device__ __forceinline__ int addr_of(ColAddr a, int u) { return bigidx(u, a.c); }
__device__ __forceinline__ int addr_of(RowAddr a, int u) { return bigidx(a.r, u); }

// W_M^{-m} from 2-level tables (Whi[m]=exp(-i*pi*m/64), Wlo[m]=exp(-i*pi*m/8192))
__device__ __forceinline__ float2 wtab(const float2* Whi, const float2* Wlo, int m) {
    return cmul(Whi[m >> 7], Wlo[m & 127]);
}

// ================= single-call cores (bhat builder only) =============
template<class AD>
__device__ __forceinline__ void dif128(float2 v[8], float2* L, AD ad, int p) {
    float sn, cs;
    __sincosf(PI_F * (float)p * (1.0f/64.0f), &sn, &cs);
    float2 w1 = make_float2(cs, -sn);
    float2 w2 = cmul(w1, w1);
    float2 w4 = cmul(w2, w2);
    BF(v[0],v[4], w1);
    BF(v[1],v[5], cmul(w1, make_float2(R2_F,-R2_F)));
    BF(v[2],v[6], make_float2(w1.y, -w1.x));
    BF(v[3],v[7], cmul(w1, make_float2(-R2_F,-R2_F)));
    float2 w2i = make_float2(w2.y, -w2.x);
    BF(v[0],v[2], w2);  BF(v[1],v[3], w2i);
    BF(v[4],v[6], w2);  BF(v[5],v[7], w2i);
    BF(v[0],v[1], w4);  BF(v[2],v[3], w4);
    BF(v[4],v[5], w4);  BF(v[6],v[7], w4);
    #pragma unroll
    for (int q = 0; q < 8; ++q) L[addr_of(ad, p + 16*q)] = v[q];
    int bb = p >> 1, r = p & 1;
    #pragma unroll
    for (int s = 0; s < 8; ++s) v[s] = L[addr_of(ad, 16*bb + r + 2*s)];
    BF(v[0],v[4], SELC(r, 1.f,0.f,                    0.92387953f,-0.38268343f));
    BF(v[1],v[5], SELC(r, 0.70710678f,-0.70710678f,   0.38268343f,-0.92387953f));
    BF(v[2],v[6], SELC(r, 0.f,-1.f,                  -0.38268343f,-0.92387953f));
    BF(v[3],v[7], SELC(r, -0.70710678f,-0.70710678f, -0.92387953f,-0.38268343f));
    BF(v[0],v[2], SELC(r, 1.f,0.f,  0.70710678f,-0.70710678f));
    BF(v[1],v[3], SELC(r, 0.f,-1.f, -0.70710678f,-0.70710678f));
    BF(v[4],v[6], SELC(r, 1.f,0.f,  0.70710678f,-0.70710678f));
    BF(v[5],v[7], SELC(r, 0.f,-1.f, -0.70710678f,-0.70710678f));
    #pragma unroll
    for (int s = 0; s < 8; s += 2) {
        float2 d = csub(v[s], v[s+1]);
        v[s] = cadd(v[s], v[s+1]);
        v[s+1] = r ? make_float2(d.y, -d.x) : d;
    }
    #pragma unroll
    for (int s = 0; s < 8; ++s) {
        float2 o = shflx1(v[s]);
        v[s] = r ? csub(o, v[s]) : cadd(v[s], o);
    }
}

// ================= 4-way cores (main kernel) =============
// HZ: inputs v[h][4..7] are implicit zeros (not loaded).
template<bool HZ, class AD>
__device__ __forceinline__ void dif128q(float2 v[4][8], float2* L, const AD* ad,
                                        int p, const float2* sWhi) {
    float2 w1 = sWhi[p];                        // exp(-i*pi*p/64)
    float2 w2 = cmul(w1, w1);
    float2 w4 = cmul(w2, w2);
    float2 w1b = cmul(w1, make_float2(R2_F,-R2_F));
    float2 w1c = make_float2(w1.y, -w1.x);
    float2 w1d = cmul(w1, make_float2(-R2_F,-R2_F));
    float2 w2i = make_float2(w2.y, -w2.x);
    #pragma unroll
    for (int h = 0; h < 4; ++h) {
        if (HZ) {
            v[h][4] = cmul(v[h][0], w1);
            v[h][5] = cmul(v[h][1], w1b);
            v[h][6] = cmul(v[h][2], w1c);
            v[h][7] = cmul(v[h][3], w1d);
        } else {
            BF(v[h][0],v[h][4], w1);
            BF(v[h][1],v[h][5], w1b);
            BF(v[h][2],v[h][6], w1c);
            BF(v[h][3],v[h][7], w1d);
        }
        BF(v[h][0],v[h][2], w2);  BF(v[h][1],v[h][3], w2i);
        BF(v[h][4],v[h][6], w2);  BF(v[h][5],v[h][7], w2i);
        BF(v[h][0],v[h][1], w4);  BF(v[h][2],v[h][3], w4);
        BF(v[h][4],v[h][5], w4);  BF(v[h][6],v[h][7], w4);
    }
    #pragma unroll
    for (int h = 0; h < 4; ++h)
        #pragma unroll
        for (int q = 0; q < 8; ++q) L[addr_of(ad[h], p + 16*q)] = v[h][q];
    int bb = p >> 1, r = p & 1;
    #pragma unroll
    for (int h = 0; h < 4; ++h)
        #pragma unroll
        for (int s = 0; s < 8; ++s) v[h][s] = L[addr_of(ad[h], 16*bb + r + 2*s)];
    #pragma unroll
    for (int h = 0; h < 4; ++h) {
        BF(v[h][0],v[h][4], SELC(r, 1.f,0.f,                    0.92387953f,-0.38268343f));
        BF(v[h][1],v[h][5], SELC(r, 0.70710678f,-0.70710678f,   0.38268343f,-0.92387953f));
        BF(v[h][2],v[h][6], SELC(r, 0.f,-1.f,                  -0.38268343f,-0.92387953f));
        BF(v[h][3],v[h][7], SELC(r, -0.70710678f,-0.70710678f, -0.92387953f,-0.38268343f));
        BF(v[h][0],v[h][2], SELC(r, 1.f,0.f,  0.70710678f,-0.70710678f));
        BF(v[h][1],v[h][3], SELC(r, 0.f,-1.f, -0.70710678f,-0.70710678f));
        BF(v[h][4],v[h][6], SELC(r, 1.f,0.f,  0.70710678f,-0.70710678f));
        BF(v[h][5],v[h][7], SELC(r, 0.f,-1.f, -0.70710678f,-0.70710678f));
        #pragma unroll
        for (int s = 0; s < 8; s += 2) {
            float2 d = csub(v[h][s], v[h][s+1]);
            v[h][s] = cadd(v[h][s], v[h][s+1]);
            v[h][s+1] = r ? make_float2(d.y, -d.x) : d;
        }
        #pragma unroll
        for (int s = 0; s < 8; ++s) {
            float2 o = shflx1(v[h][s]);
            v[h][s] = r ? csub(o, v[h][s]) : cadd(v[h][s], o);
        }
    }
}

// HOUT: only lo outputs v[h][0..3] of the final stage are produced.
template<bool HOUT, class AD>
__device__ __forceinline__ void dit128q(float2 v[4][8], float2* L, const AD* ad,
                                        int p, const float2* sWhi) {
    int bb = p >> 1, r = p & 1;
    #pragma unroll
    for (int h = 0; h < 4; ++h) {
        #pragma unroll
        for (int s = 0; s < 8; ++s) {
            float2 o = shflx1(v[h][s]);
            v[h][s] = r ? csub(o, v[h][s]) : cadd(v[h][s], o);
        }
        #pragma unroll
        for (int s = 0; s < 8; s += 2) {
            float2 bq = v[h][s+1];
            if (r) bq = make_float2(-bq.y, bq.x);
            v[h][s+1] = csub(v[h][s], bq);
            v[h][s] = cadd(v[h][s], bq);
        }
        BT(v[h][0],v[h][2], SELC(r, 1.f,0.f,  0.70710678f,0.70710678f));
        BT(v[h][1],v[h][3], SELC(r, 0.f,1.f, -0.70710678f,0.70710678f));
        BT(v[h][4],v[h][6], SELC(r, 1.f,0.f,  0.70710678f,0.70710678f));
        BT(v[h][5],v[h][7], SELC(r, 0.f,1.f, -0.70710678f,0.70710678f));
        BT(v[h][0],v[h][4], SELC(r, 1.f,0.f,                   0.92387953f,0.38268343f));
        BT(v[h][1],v[h][5], SELC(r, 0.70710678f,0.70710678f,   0.38268343f,0.92387953f));
        BT(v[h][2],v[h][6], SELC(r, 0.f,1.f,                  -0.38268343f,0.92387953f));
        BT(v[h][3],v[h][7], SELC(r, -0.70710678f,0.70710678f, -0.92387953f,0.38268343f));
    }
    #pragma unroll
    for (int h = 0; h < 4; ++h)
        #pragma unroll
        for (int s = 0; s < 8; ++s) L[addr_of(ad[h], 16*bb + r + 2*s)] = v[h][s];
    #pragma unroll
    for (int h = 0; h < 4; ++h)
        #pragma unroll
        for (int q = 0; q < 8; ++q) v[h][q] = L[addr_of(ad[h], p + 16*q)];
    float2 w1 = make_float2(sWhi[p].x, -sWhi[p].y);   // exp(+i*pi*p/64)
    float2 w2 = cmul(w1, w1);
    float2 w4 = cmul(w2, w2);
    float2 w2j = make_float2(-w2.y, w2.x);
    float2 w1b = cmul(w1, make_float2(R2_F, R2_F));
    float2 w1c = make_float2(-w1.y, w1.x);
    float2 w1d = cmul(w1, make_float2(-R2_F, R2_F));
    #pragma unroll
    for (int h = 0; h < 4; ++h) {
        BT(v[h][0],v[h][1], w4); BT(v[h][2],v[h][3], w4);
        BT(v[h][4],v[h][5], w4); BT(v[h][6],v[h][7], w4);
        BT(v[h][0],v[h][2], w2);  BT(v[h][1],v[h][3], w2j);
        BT(v[h][4],v[h][6], w2);  BT(v[h][5],v[h][7], w2j);
        if (HOUT) {
            v[h][0] = cadd(v[h][0], cmul(v[h][4], w1));
            v[h][1] = cadd(v[h][1], cmul(v[h][5], w1b));
            v[h][2] = cadd(v[h][2], cmul(v[h][6], w1c));
            v[h][3] = cadd(v[h][3], cmul(v[h][7], w1d));
        } else {
            BT(v[h][0],v[h][4], w1);
            BT(v[h][1],v[h][5], w1b);
            BT(v[h][2],v[h][6], w1c);
            BT(v[h][3],v[h][7], w1d);
        }
    }
}

// ---------------- Bhat builder: one block per b (R3-proven) ------
__global__ __launch_bounds__(1024) void eofft_bhat(const float* __restrict__ rpm,
                                                   float2* __restrict__ bhat) {
    extern __shared__ float2 L[];
    int tid = threadIdx.x;
    int f = tid >> 4, p = tid & 15;
    int b = blockIdx.x;
    int n = compute_n(rpm[b]);
    int two_n = 2 * n;
    float inv_n = 1.0f / (float)n;

    #pragma unroll
    for (int i = 0; i < 16; ++i) {
        int t = i * 1024 + tid;
        int mm = min(t, Mm - t);
        int ph = (mm * mm) % two_n;
        float sn, cs; __sincosf(PI_F * (float)ph * inv_n, &sn, &cs);
        L[bigidx(t >> 7, t & 127)] = make_float2(cs, sn);   // exp(+i b_phase)
    }
    __syncthreads();
    #pragma unroll
    for (int c0 = 0; c0 < 128; c0 += 64) {
        int t1 = c0 + f;
        float2 v[8];
        #pragma unroll
        for (int q = 0; q < 8; ++q) v[q] = L[bigidx(p + 16*q, t1)];
        dif128(v, L, ColAddr{t1}, p);
        int bb = p >> 1, r = p & 1;
        #pragma unroll
        for (int s = 0; s < 8; ++s) {
            int j = 16*bb + r + 2*s;
            int k2 = __brev((unsigned)j) >> 25;
            float sn, cs;
            __sincosf(-TWO_PI_F * (float)(t1 * k2) * (1.0f/16384.0f), &sn, &cs);
            L[bigidx(j, t1)] = cmul(v[s], make_float2(cs, sn));
        }
    }
    __syncthreads();
    #pragma unroll
    for (int r0 = 0; r0 < 128; r0 += 64) {
        int j = r0 + f;
        float2 v[8];
        #pragma unroll
        for (int q = 0; q < 8; ++q) v[q] = L[bigidx(j, p + 16*q)];
        dif128(v, L, RowAddr{j}, p);
        float2* bo = bhat + ((size_t)b << 14) + (j << 7) + (p << 3);
        #pragma unroll
        for (int s = 0; s < 8; ++s) bo[s] = v[s];
    }
}

// ---------------- main: one block per (b,ch), 512 threads, 4-way ILP --------
__global__ __launch_bounds__(512, 2) void eofft_main(const float* __restrict__ x,
                                                     const float* __restrict__ rpm,
                                                     const float2* __restrict__ bhat,
                                                     float* __restrict__ out) {
    extern __shared__ float2 L[];
    __shared__ float2 sWhi[128];
    __shared__ float2 sWlo[128];
    int tid = threadIdx.x;
    int f = tid >> 4, p = tid & 15;      // f in [0,32)
    int bb = p >> 1, r = p & 1;
    int b = blockIdx.x & 63;             // ch*64+b: channel-siblings share an XCD
    int ch = blockIdx.x >> 6;

    if (tid < 128) {
        float sn, cs; __sincosf(PI_F * (float)tid * (1.0f/64.0f), &sn, &cs);
        sWhi[tid] = make_float2(cs, -sn);
    } else if (tid < 256) {
        int m = tid - 128;
        float sn, cs; __sincosf(PI_F * (float)m * (1.0f/8192.0f), &sn, &cs);
        sWlo[m] = make_float2(cs, -sn);
    }
    int n = compute_n(rpm[b]);
    int two_n = 2 * n;
    float inv_n = 1.0f / (float)n;
    // chirp quadratic-phase recurrence (t steps by 512):
    // d_phase(t) = (t+512)^2 - t^2 = 1024t + 262144 ; dd step = 524288
    float sn, cs;
    __sincosf(PI_F * (float)((tid * tid) % two_n) * inv_n, &sn, &cs);
    float2 u = make_float2(cs, -sn);
    __sincosf(PI_F * (float)((1024 * tid + 262144) % two_n) * inv_n, &sn, &cs);
    float2 dd = make_float2(cs, -sn);
    __sincosf(PI_F * (float)(524288 % two_n) * inv_n, &sn, &cs);
    float2 Cst = make_float2(cs, -sn);

    // ---- build a = x * exp(-i a_phase); rows t2>=64 never touched (HZ trim)
    {
        const float* xb = x + ((size_t)b << 16) + ch;
        #pragma unroll
        for (int i = 0; i < 16; ++i) {
            int t = i * 512 + tid;               // t < 8192
            float xv = xb[(size_t)t << 3];
            L[bigidx(t >> 7, t & 127)] = make_float2(xv * u.x, xv * u.y);
            u = cmul(u, dd); dd = cmul(dd, Cst);
        }
    }
    __syncthreads();
    float2 v[4][8];
    // ---- phase A: fwd FFT over t2, 4 columns per thread; twiddle chains
    {
        ColAddr ad[4] = { {f}, {f+32}, {f+64}, {f+96} };
        #pragma unroll
        for (int h = 0; h < 4; ++h)
            #pragma unroll
            for (int q = 0; q < 4; ++q) v[h][q] = L[bigidx(p + 16*q, ad[h].c)];
        dif128q<true>(v, L, ad, p, sWhi);
        int k2base = __brev((unsigned)(16*bb + r)) >> 25;
        #pragma unroll
        for (int h = 0; h < 4; ++h) {
            int t1 = ad[h].c;
            float2 cur = wtab(sWhi, sWlo, t1 * k2base);
            float2 w8  = wtab(sWhi, sWlo, 8 * t1);
            #pragma unroll
            for (int e = 0; e < 8; ++e) {
                const int s = ((e & 1) << 2) | (e & 2) | ((e & 4) >> 2); // brev3(e)
                L[bigidx(16*bb + r + 2*s, t1)] = cmul(v[h][s], cur);
                cur = cmul(cur, w8);
            }
        }
    }
    __syncthreads();
    // ---- phase B: 4 rows per thread: fwd over t1, *Bhat, inv over k1, twiddle
    {
        RowAddr ad[4] = { {f}, {f+32}, {f+64}, {f+96} };
        #pragma unroll
        for (int h = 0; h < 4; ++h)
            #pragma unroll
            for (int q = 0; q < 8; ++q) v[h][q] = L[bigidx(ad[h].r, p + 16*q)];
        // issue Bhat loads now; FFT core covers their latency
        const float2* bhp = bhat + ((size_t)b << 14) + (p << 3);
        float2 bh[4][8];
        #pragma unroll
        for (int h = 0; h < 4; ++h)
            #pragma unroll
            for (int s = 0; s < 8; ++s) bh[h][s] = bhp[((size_t)ad[h].r << 7) + s];
        dif128q<false>(v, L, ad, p, sWhi);
        #pragma unroll
        for (int h = 0; h < 4; ++h)
            #pragma unroll
            for (int s = 0; s < 8; ++s) v[h][s] = cmul(v[h][s], bh[h][s]);
        dit128q<false>(v, L, ad, p, sWhi);
        #pragma unroll
        for (int h = 0; h < 4; ++h) {
            int j = ad[h].r;
            int k2v = __brev((unsigned)j) >> 25;
            float2 cur = wtab(sWhi, sWlo, k2v * p);
            float2 w16 = wtab(sWhi, sWlo, 16 * k2v);
            #pragma unroll
            for (int q = 0; q < 8; ++q) {
                // * exp(+2pi i k2 t1/M) = conj(cur)
                L[bigidx(j, p + 16*q)] = cmul(v[h][q], make_float2(cur.x, -cur.y));
                cur = cmul(cur, w16);
            }
        }
    }
    __syncthreads();
    // ---- phase C: inverse FFT over k2 per column; keep t2 < 64; |.|/M
    {
        ColAddr ad[4] = { {f}, {f+32}, {f+64}, {f+96} };
        #pragma unroll
        for (int h = 0; h < 4; ++h)
            #pragma unroll
            for (int s = 0; s < 8; ++s) v[h][s] = L[bigidx(16*bb + r + 2*s, ad[h].c)];
        dit128q<true>(v, L, ad, p, sWhi);
        #pragma unroll
        for (int h = 0; h < 4; ++h) {
            int t1 = ad[h].c;
            float* ob = out + (((size_t)(b << 13) + t1) << 3) + ch;
            #pragma unroll
            for (int q = 0; q < 4; ++q) {
                int t2 = p + 16*q;
                float2 z = v[h][q];
                ob[(size_t)t2 << 10] = sqrtf(z.x*z.x + z.y*z.y) * (1.0f/16384.0f);
            }
        }
    }
}

// ---------------- launch ----------------
extern "C" void kernel_launch(void* const* d_in, const int* in_sizes, int n_in,
                              void* d_out, int out_size, void* d_ws, size_t ws_size,
                              hipStream_t stream) {
    const float* x   = (const float*)d_in[0];
    const float* rpm = (const float*)d_in[1];
    float* outF = (float*)d_out;
    float2* bhat = (float2*)d_ws;                    // 64*16384 float2 = 8 MiB

    eofft_bhat<<<Bn, 1024, 131072, stream>>>(rpm, bhat);
    eofft_main<<<Bn * 8, 512, 131072, stream>>>(x, rpm, bhat, outF);
}